// Round 6
// baseline (204.750 us; speedup 1.0000x reference)
//
#include <hip/hip_runtime.h>

#define TT 14
#define LL 26
#define EE 128
#define NB 16384
#define BPB 8              // batches per block
#define ROWS (BPB * TT)    // 112 (b,t) rows per block
#define EPAD 27            // odd pad -> bank-bijective emis access
#define SPAD 33            // stage row pad: (33r+e)%32=(r+e)%32 -> <=2-way
#define CH 32              // e-values per chunk
#define NCH (EE / CH)      // 4 chunks

// ---------------------------------------------------------------------------
// Setup: fold conv into an effective emission matrix.
//   Weff[e][l] = sum_{ky,kx} conv_w[ky][kx] * Wmat[l][oy*8+ox]
//   be[l]      = conv_b * sum_e Wmat[l][e]
// ---------------------------------------------------------------------------
__global__ __launch_bounds__(256) void crf_setup(
    const float* __restrict__ conv_w, const float* __restrict__ conv_b,
    const float* __restrict__ params, float* __restrict__ weff,
    float* __restrict__ be) {
  int idx = blockIdx.x * 256 + threadIdx.x;
  if (idx < EE * LL) {
    int e = idx / LL, l = idx - e * LL;
    int iy = e >> 3, ix = e & 7;
    float s = 0.f;
    for (int ky = 0; ky < 5; ++ky) {
      int oy = iy - ky + 2;
      if (oy < 0 || oy >= 16) continue;
      for (int kx = 0; kx < 5; ++kx) {
        int ox = ix - kx + 2;
        if (ox < 0 || ox >= 8) continue;
        s += conv_w[ky * 5 + kx] * params[l * EE + oy * 8 + ox];
      }
    }
    weff[e * LL + l] = s;  // [e][l]: main-kernel reads are wave-uniform
  }
  if (idx < LL) {
    float s = 0.f;
    for (int e = 0; e < EE; ++e) s += params[idx * EE + e];
    be[idx] = conv_b[0] * s;
  }
}

// ---------------------------------------------------------------------------
// Fused emission GEMM + Viterbi + backtrack. One block = 8 batches.
// GEMM: 256 threads; X staged through LDS in 32-e chunks (coalesced global
// loads, loaded ONCE per block); thread (half, r) computes 13 labels of row
// r (wave-uniform half -> weff stays s_loaded, <=52 live W floats).
// Chunk c+1 prefetched into 4 float4 regs while chunk c computes (T14).
// ---------------------------------------------------------------------------
__global__ __launch_bounds__(256, 6) void crf_main(
    const float* __restrict__ X, const float* __restrict__ params,
    const float* __restrict__ weff, const float* __restrict__ be,
    float* __restrict__ out) {
  __shared__ float stage[ROWS * SPAD];             // 14784 B, union'd w/ emis
  __shared__ float Ts[LL * LL];                    // 2704 B
  __shared__ unsigned char bp_s[BPB][TT - 1][28];  // 2912 B
  float* emis_s = stage;                           // reuse after GEMM

  const int tid = threadIdx.x;
  const int b0 = blockIdx.x * BPB;
  const float4* Xv =
      reinterpret_cast<const float4*>(X) + (size_t)b0 * TT * 32;

  for (int i = tid; i < LL * LL; i += 256) Ts[i] = params[LL * EE + i];

  // ---- Phase 1: emissions.
  const int half = tid >> 7;   // wave-uniform (wave 0,1 -> 0; wave 2,3 -> 1)
  const int r = tid & 127;     // row within block
  const int lb = half * 13;    // wave-uniform label base

  float acc[13];
#pragma unroll
  for (int l = 0; l < 13; ++l) acc[l] = 0.f;

  // Staging regs: fid = k*256+tid; row = fid>>3, quad q = fid&7 (8 f4/row).
  float4 xb[4];
#pragma unroll
  for (int k = 0; k < 4; ++k) {
    int fid = k * 256 + tid;
    if (fid < ROWS * 8) xb[k] = Xv[(size_t)(fid >> 3) * 32 + (fid & 7)];
  }

  for (int c = 0; c < NCH; ++c) {
    if (c > 0) __syncthreads();  // previous chunk fully consumed
    // regs -> LDS (implicit vmcnt wait on xb loads)
#pragma unroll
    for (int k = 0; k < 4; ++k) {
      int fid = k * 256 + tid;
      if (fid < ROWS * 8) {
        float* p = &stage[(fid >> 3) * SPAD + (fid & 7) * 4];
        p[0] = xb[k].x; p[1] = xb[k].y; p[2] = xb[k].z; p[3] = xb[k].w;
      }
    }
    // issue next chunk's loads (in flight during compute below)
    if (c + 1 < NCH) {
#pragma unroll
      for (int k = 0; k < 4; ++k) {
        int fid = k * 256 + tid;
        if (fid < ROWS * 8)
          xb[k] = Xv[(size_t)(fid >> 3) * 32 + (c + 1) * 8 + (fid & 7)];
      }
    }
    __syncthreads();  // stage ready
    if (r < ROWS) {
#pragma unroll
      for (int s = 0; s < CH / 4; ++s) {  // 8 sub-chunks of 4 e-values
        const float* xs = &stage[r * SPAD + s * 4];
        const float vx = xs[0], vy = xs[1], vz = xs[2], vw = xs[3];
        const float* w = weff + (c * CH + s * 4) * LL + lb;  // s_load
#pragma unroll
        for (int l = 0; l < 13; ++l)
          acc[l] += vx * w[l] + vy * w[LL + l] + vz * w[2 * LL + l] +
                    vw * w[3 * LL + l];
      }
    }
  }
  __syncthreads();  // last chunk consumed everywhere; stage free for emis
  if (r < ROWS) {
#pragma unroll
    for (int l = 0; l < 13; ++l)
      emis_s[r * EPAD + lb + l] = acc[l] + be[lb + l];  // be: s_load
  }
  __syncthreads();

  // ---- Phase 2: Viterbi. 8 groups of 32 lanes; group g = batch, lane j =
  //      label. Single pass (R4-verified code).
  const int g = tid >> 5;                  // 0..7
  const int j = tid & 31;
  const int jj = (j < LL) ? j : (LL - 1);

  float Tcol[LL];
#pragma unroll
  for (int i = 0; i < LL; ++i) Tcol[i] = Ts[i * LL + jj];  // Trans[i][j]

  float alpha = emis_s[(g * TT + 0) * EPAD + jj];
  for (int t = 1; t < TT; ++t) {
    float m = -__builtin_inff();
    int bp = 0;
#pragma unroll
    for (int i = 0; i < LL; ++i) {
      float a_i = __shfl(alpha, i, 32);
      float s = a_i + Tcol[i];
      if (s > m) { m = s; bp = i; }        // strict > : first-index tie-break
    }
    alpha = m + emis_s[(g * TT + t) * EPAD + jj];
    if (j < LL) bp_s[g][t - 1][j] = (unsigned char)bp;
  }

  // argmax over labels (max value, lowest index on tie)
  float val = (j < LL) ? alpha : -__builtin_inff();
  int idx = j;
#pragma unroll
  for (int off = 16; off >= 1; off >>= 1) {
    float v2 = __shfl_xor(val, off, 32);
    int i2 = __shfl_xor(idx, off, 32);
    if (v2 > val || (v2 == val && i2 < idx)) { val = v2; idx = i2; }
  }

  __syncthreads();  // bp_s writes visible before backtrack

  if (j == 0) {
    const int b = b0 + g;
    out[(size_t)NB * TT + b] = val;  // score
    int lbl = idx;
    for (int t = TT - 1; t >= 1; --t) {
      out[(size_t)b * TT + t] = (float)lbl;
      lbl = bp_s[g][t - 1][lbl];
    }
    out[(size_t)b * TT + 0] = (float)lbl;
  }
}

extern "C" void kernel_launch(void* const* d_in, const int* in_sizes, int n_in,
                              void* d_out, int out_size, void* d_ws,
                              size_t ws_size, hipStream_t stream) {
  const float* X = (const float*)d_in[0];
  const float* conv_w = (const float*)d_in[1];
  const float* conv_b = (const float*)d_in[2];
  const float* params = (const float*)d_in[3];
  float* out = (float*)d_out;
  float* weff = (float*)d_ws;  // 3328 floats
  float* be = weff + EE * LL;  // 26 floats

  hipLaunchKernelGGL(crf_setup, dim3(13), dim3(256), 0, stream, conv_w, conv_b,
                     params, weff, be);
  hipLaunchKernelGGL(crf_main, dim3(NB / BPB), dim3(256), 0, stream, X, params,
                     weff, be, out);
}

// Round 7
// 146.530 us; speedup vs baseline: 1.3973x; 1.3973x over previous
//
#include <hip/hip_runtime.h>
#include <stdint.h>

#define TT 14
#define LL 26
#define EE 128
#define NB 16384
#define BPB 8              // batches per block
#define ROWS (BPB * TT)    // 112 (b,t) rows per block
#define EPAD 27            // odd pad -> bank-bijective emis access
#define CH 32              // e-values per chunk (= 128 B/row = bank period)
#define NCH (EE / CH)      // 4 chunks
#define SLOTS (ROWS * 8)   // 896 16B-slots per chunk
#define NLD (SLOTS / 64)   // 14 global_load_lds instrs per chunk

// Async global->LDS, 16 B per lane: lane's data lands at ldsbase + lane*16.
__device__ __forceinline__ void gld16(void* lds_base_uniform, const void* g) {
  __builtin_amdgcn_global_load_lds(
      (const __attribute__((address_space(1))) unsigned int*)g,
      (__attribute__((address_space(3))) unsigned int*)lds_base_uniform,
      16, 0, 0);
}

// ---------------------------------------------------------------------------
// Setup: fold conv into an effective emission matrix.
//   Weff[e][l] = sum_{ky,kx} conv_w[ky][kx] * Wmat[l][oy*8+ox]
//   be[l]      = conv_b * sum_e Wmat[l][e]
// ---------------------------------------------------------------------------
__global__ __launch_bounds__(256) void crf_setup(
    const float* __restrict__ conv_w, const float* __restrict__ conv_b,
    const float* __restrict__ params, float* __restrict__ weff,
    float* __restrict__ be) {
  int idx = blockIdx.x * 256 + threadIdx.x;
  if (idx < EE * LL) {
    int e = idx / LL, l = idx - e * LL;
    int iy = e >> 3, ix = e & 7;
    float s = 0.f;
    for (int ky = 0; ky < 5; ++ky) {
      int oy = iy - ky + 2;
      if (oy < 0 || oy >= 16) continue;
      for (int kx = 0; kx < 5; ++kx) {
        int ox = ix - kx + 2;
        if (ox < 0 || ox >= 8) continue;
        s += conv_w[ky * 5 + kx] * params[l * EE + oy * 8 + ox];
      }
    }
    weff[e * LL + l] = s;  // [e][l]: main-kernel reads are wave-uniform
  }
  if (idx < LL) {
    float s = 0.f;
    for (int e = 0; e < EE; ++e) s += params[idx * EE + e];
    be[idx] = conv_b[0] * s;
  }
}

// ---------------------------------------------------------------------------
// Fused emission GEMM + Viterbi + backtrack. One block = 8 batches.
// X staged once via global_load_lds (async, coalesced, no VGPRs) with
// pre-swizzled global source: LDS slot (r,q) holds global quad q^(r&7) of
// row r -> compute-phase ds_read_b128 is bank-conflict-free.
// Thread (half, r): 13 labels of row r; per-label FMA chain order identical
// to the absmax-0.0 lineage (ascending e quads, x/y/z/w).
// ---------------------------------------------------------------------------
__global__ __launch_bounds__(256, 5) void crf_main(
    const float* __restrict__ X, const float* __restrict__ params,
    const float* __restrict__ weff, const float* __restrict__ be,
    float* __restrict__ out) {
  __shared__ float stage[2][SLOTS * 4];  // 2 x 14336 B; buf0 -> emis,
  float* emis_s = stage[0];              // buf1 -> bp after GEMM
  unsigned char* bp_s = (unsigned char*)stage[1];  // [BPB][13][28]

  const int tid = threadIdx.x;
  const int b0 = blockIdx.x * BPB;
  const char* Xblk = (const char*)(X + (size_t)b0 * TT * EE);

  const int wv = tid >> 6;     // wave 0..3
  const int lam = tid & 63;    // lane
  const int half = tid >> 7;   // wave-uniform label half
  const int r = tid & 127;     // row within block
  const int lb = half * 13;    // wave-uniform label base

  // Per-lane staging geometry: instr i covers slots [i*64, i*64+64).
  const int srs = (lam >> 3);  // row offset within instr's 8-row span
  const int sqs = lam & 7;     // quad slot

  // ---- Prologue: stage chunk 0 into buf0.
  {
    for (int i = wv; i < NLD; i += 4) {
      int rs = i * 8 + srs;
      int gq = sqs ^ (rs & 7);  // pre-swizzled source quad
      gld16(stage[0] + i * 256, Xblk + (size_t)rs * 512 + gq * 16);
    }
  }

  float acc[13];
#pragma unroll
  for (int l = 0; l < 13; ++l) acc[l] = 0.f;

  for (int c = 0; c < NCH; ++c) {
    // Issue next chunk's staging before computing this one (overlap).
    if (c + 1 < NCH) {
      float* nbuf = stage[(c + 1) & 1];
      for (int i = wv; i < NLD; i += 4) {
        int rs = i * 8 + srs;
        int gq = sqs ^ (rs & 7);
        gld16(nbuf + i * 256,
              Xblk + (size_t)rs * 512 + (size_t)((c + 1) * CH / 4 + gq) * 16);
      }
    }
    if (c == 0) __syncthreads();  // chunk-0 data visible (vmcnt drained)
    const float* sb = stage[c & 1];
    if (r < ROWS) {
#pragma unroll
      for (int q = 0; q < 8; ++q) {
        const float4 v = *reinterpret_cast<const float4*>(
            &sb[(r * 8 + (q ^ (r & 7))) * 4]);
        const float* w = weff + (c * CH + q * 4) * LL + lb;  // s_load
#pragma unroll
        for (int l = 0; l < 13; ++l)
          acc[l] += v.x * w[l] + v.y * w[LL + l] + v.z * w[2 * LL + l] +
                    v.w * w[3 * LL + l];
      }
    }
    __syncthreads();  // this buf consumed; next chunk's data visible
  }

  // ---- emis into buf0 (its c=3 readers finished; c=3 read buf1).
  if (r < ROWS) {
#pragma unroll
    for (int l = 0; l < 13; ++l)
      emis_s[r * EPAD + lb + l] = acc[l] + be[lb + l];  // be: s_load
  }
  __syncthreads();

  // ---- Phase 2: Viterbi. 8 groups of 32 lanes; group g = batch, lane j =
  //      label (R4-verified code; Tcol from global params, R3-verified).
  const int g = tid >> 5;                  // 0..7
  const int j = tid & 31;
  const int jj = (j < LL) ? j : (LL - 1);

  const float* Tr = params + LL * EE;
  float Tcol[LL];
#pragma unroll
  for (int i = 0; i < LL; ++i) Tcol[i] = Tr[i * LL + jj];  // Trans[i][j]

  float alpha = emis_s[(g * TT + 0) * EPAD + jj];
  for (int t = 1; t < TT; ++t) {
    float m = -__builtin_inff();
    int bp = 0;
#pragma unroll
    for (int i = 0; i < LL; ++i) {
      float a_i = __shfl(alpha, i, 32);
      float s = a_i + Tcol[i];
      if (s > m) { m = s; bp = i; }        // strict > : first-index tie-break
    }
    alpha = m + emis_s[(g * TT + t) * EPAD + jj];
    if (j < LL) bp_s[(g * 13 + (t - 1)) * 28 + j] = (unsigned char)bp;
  }

  // argmax over labels (max value, lowest index on tie)
  float val = (j < LL) ? alpha : -__builtin_inff();
  int idx = j;
#pragma unroll
  for (int off = 16; off >= 1; off >>= 1) {
    float v2 = __shfl_xor(val, off, 32);
    int i2 = __shfl_xor(idx, off, 32);
    if (v2 > val || (v2 == val && i2 < idx)) { val = v2; idx = i2; }
  }

  __syncthreads();  // bp_s writes visible before backtrack

  if (j == 0) {
    const int b = b0 + g;
    out[(size_t)NB * TT + b] = val;  // score
    int lbl = idx;
    for (int t = TT - 1; t >= 1; --t) {
      out[(size_t)b * TT + t] = (float)lbl;
      lbl = bp_s[(g * 13 + (t - 1)) * 28 + lbl];
    }
    out[(size_t)b * TT + 0] = (float)lbl;
  }
}

extern "C" void kernel_launch(void* const* d_in, const int* in_sizes, int n_in,
                              void* d_out, int out_size, void* d_ws,
                              size_t ws_size, hipStream_t stream) {
  const float* X = (const float*)d_in[0];
  const float* conv_w = (const float*)d_in[1];
  const float* conv_b = (const float*)d_in[2];
  const float* params = (const float*)d_in[3];
  float* out = (float*)d_out;
  float* weff = (float*)d_ws;  // 3328 floats
  float* be = weff + EE * LL;  // 26 floats

  hipLaunchKernelGGL(crf_setup, dim3(13), dim3(256), 0, stream, conv_w, conv_b,
                     params, weff, be);
  hipLaunchKernelGGL(crf_main, dim3(NB / BPB), dim3(256), 0, stream, X, params,
                     weff, be, out);
}